// Round 12
// baseline (328.486 us; speedup 1.0000x reference)
//
#include <hip/hip_runtime.h>

#define N_NODES 50000
#define N_EDGES 800000
#define N_GRAPHS 2000
#define BN_EPS 1e-5f
#define FSHARD 12500  // fill: N_NODES / 4
#define BCAP 64       // bucket capacity per node (P(deg>64) ~ 1e-22 @ Poisson(16))

typedef unsigned short ushort_t;
typedef unsigned int uint_t;
typedef unsigned char uchar_t;
using bf16x8 = __attribute__((ext_vector_type(8))) short;
using f32x4  = __attribute__((ext_vector_type(4))) float;
using vf2    = __attribute__((ext_vector_type(2))) float;

__device__ inline float bf_lo(uint_t u) { return __uint_as_float(u << 16); }
__device__ inline float bf_hi(uint_t u) { return __uint_as_float(u & 0xffff0000u); }
__device__ inline ushort_t f2bf(float f) {  // round-to-nearest-even
  uint_t u = __float_as_uint(f);
  return (ushort_t)((u + 0x7fffu + ((u >> 16) & 1u)) >> 16);
}
__device__ inline uint_t pack2(float a, float b) {
  return (uint_t)f2bf(a) | ((uint_t)f2bf(b) << 16);
}
// uint4-wide fp8 accumulate into four f32x4 SSA vectors (constant-indexed —
// R6's spill was `float a[16]` array-param decay -> local memory, rule #20).
__device__ inline void cvt16(uint4 u, f32x4& A, f32x4& B, f32x4& C, f32x4& D) {
  vf2 f;
  f = __builtin_amdgcn_cvt_pk_f32_fp8((int)u.x, false); A[0] += f[0]; A[1] += f[1];
  f = __builtin_amdgcn_cvt_pk_f32_fp8((int)u.x, true);  A[2] += f[0]; A[3] += f[1];
  f = __builtin_amdgcn_cvt_pk_f32_fp8((int)u.y, false); B[0] += f[0]; B[1] += f[1];
  f = __builtin_amdgcn_cvt_pk_f32_fp8((int)u.y, true);  B[2] += f[0]; B[3] += f[1];
  f = __builtin_amdgcn_cvt_pk_f32_fp8((int)u.z, false); C[0] += f[0]; C[1] += f[1];
  f = __builtin_amdgcn_cvt_pk_f32_fp8((int)u.z, true);  C[2] += f[0]; C[3] += f[1];
  f = __builtin_amdgcn_cvt_pk_f32_fp8((int)u.w, false); D[0] += f[0]; D[1] += f[1];
  f = __builtin_amdgcn_cvt_pk_f32_fp8((int)u.w, true);  D[2] += f[0]; D[3] += f[1];
}

// ================================================================ prep + bucket-fill (one launch)
// Bucket CSR: colb[d*64 + p] via ONE device-scope atomic pass; cursor doubles
// as degree. FLOOR EVIDENCE (~43-45us, atomic op-rate ~18G/s): R6 3-phase LDS
// histogram (+100us), R8 XCD-local scope (+36us), R11 cursor line-padding
// (no change) all falsified. Do not revisit without new counter evidence.
#define WP0 (128 * 96)
#define WP1 (128 * 256)
__global__ void prep_fill_kernel(const float* __restrict__ Wl0,
                                 const float* __restrict__ Wr0,
                                 const float* __restrict__ Wl,
                                 const float* __restrict__ Wr,
                                 const float* __restrict__ x,
                                 const int* __restrict__ src,
                                 const int* __restrict__ dst,
                                 ushort_t* __restrict__ WT0,
                                 ushort_t* __restrict__ WT1,
                                 ushort_t* __restrict__ WT2,
                                 uint_t* __restrict__ xb,
                                 float* __restrict__ stats,
                                 int* __restrict__ cursor,
                                 ushort_t* __restrict__ colb,
                                 uchar_t* __restrict__ Hza,
                                 uchar_t* __restrict__ Hzb,
                                 int prep_blocks) {
  if ((int)blockIdx.x >= prep_blocks) {
    // ---- sharded bucket fill (4 shards for cursor/colb L2 locality)
    const int b2 = blockIdx.x - prep_blocks;
    const int shard = b2 & 3;
    const int lo = shard * FSHARD, hi = lo + FSHARD;
    const int nb = (gridDim.x - prep_blocks) >> 2, blk = b2 >> 2;
    for (int e = blk * blockDim.x + threadIdx.x; e < N_EDGES;
         e += nb * blockDim.x) {
      int d = dst[e];
      if (d >= lo && d < hi) {
        int p = atomicAdd(&cursor[d], 1);
        if (p < BCAP) colb[((size_t)d << 6) + p] = (ushort_t)src[e];
      }
    }
    return;
  }
  int idx = blockIdx.x * blockDim.x + threadIdx.x;
  if (idx < 768) stats[idx] = 0.f;
  if (idx < 32) {  // sentinel zero rows (fp8) for masked gather tails
    ((uint_t*)(Hza + (size_t)N_NODES * 128))[idx] = 0;
    ((uint_t*)(Hzb + (size_t)N_NODES * 128))[idx] = 0;
  }
  if (idx < WP0) {
    int c = idx / 96, k = idx - c * 96;
    float v = 0.f;
    if (k < 38) v = Wl0[k * 128 + c];
    else if (k < 76) v = Wr0[(k - 38) * 128 + c];
    WT0[(k >> 5) * 4096 + c * 32 + (k & 31)] = f2bf(v);
  } else if (idx < WP0 + 2 * WP1) {
    int i2 = idx - WP0;
    int layer = i2 / WP1;
    int j = i2 - layer * WP1;
    int c = j / 256, k = j - c * 256;
    const float* L = Wl + layer * 16384;
    const float* R = Wr + layer * 16384;
    float v = (k < 128) ? L[k * 128 + c] : R[(k - 128) * 128 + c];
    ushort_t* W = layer ? WT2 : WT1;
    W[(k >> 5) * 4096 + c * 32 + (k & 31)] = f2bf(v);
  } else if (idx < WP0 + 2 * WP1 + (N_NODES + 1) * 20) {
    // xb rows 0..N_NODES (row N_NODES = sentinel zero row for masked gather0)
    int j = idx - (WP0 + 2 * WP1);
    int row = j / 20, c2 = (j - row * 20) * 2;
    float v0 = (row < N_NODES && c2 < 38) ? x[row * 38 + c2] : 0.f;
    float v1 = (row < N_NODES && c2 + 1 < 38) ? x[row * 38 + c2 + 1] : 0.f;
    xb[j] = pack2(v0, v1);
  }
}

// ================================================================ normalize
// Hn[row] = fp8(relu(bn(P[row]))) — per-node, so the gather never redoes BN.
__global__ __launch_bounds__(256) void normalize_kernel(
    const ushort_t* __restrict__ P, const float* __restrict__ stats,
    const float* __restrict__ gamma, const float* __restrict__ beta,
    uchar_t* __restrict__ Hn) {
  __shared__ float ssc[256];
  const int tid = threadIdx.x;
  if (tid < 128) {
    const float invN = 1.0f / (float)N_NODES;
    float mean = stats[tid] * invN;
    float var = stats[128 + tid] * invN - mean * mean;
    float s = gamma[tid] * rsqrtf(var + BN_EPS);
    ssc[tid] = s;
    ssc[128 + tid] = beta[tid] - mean * s;
  }
  __syncthreads();
  int idx = blockIdx.x * 256 + tid;  // segment id = row*16 + seg (8 cols each)
  if (idx >= N_NODES * 16) return;
  int c0 = (idx & 15) * 8;
  uint4 u = *(const uint4*)(P + (size_t)idx * 8);
  uint_t in[4] = {u.x, u.y, u.z, u.w};
  float f[8];
#pragma unroll
  for (int p = 0; p < 4; p++) {
    int c = c0 + 2 * p;
    f[2 * p]     = fmaxf(bf_lo(in[p]) * ssc[c] + ssc[128 + c], 0.f);
    f[2 * p + 1] = fmaxf(bf_hi(in[p]) * ssc[c + 1] + ssc[128 + c + 1], 0.f);
  }
  int lo = __builtin_amdgcn_cvt_pk_fp8_f32(f[0], f[1], 0, false);
  lo = __builtin_amdgcn_cvt_pk_fp8_f32(f[2], f[3], lo, true);
  int hi = __builtin_amdgcn_cvt_pk_fp8_f32(f[4], f[5], 0, false);
  hi = __builtin_amdgcn_cvt_pk_fp8_f32(f[6], f[7], hi, true);
  uint2 o;
  o.x = (uint_t)lo;
  o.y = (uint_t)hi;
  *((uint2*)(Hn + (size_t)idx * 8)) = o;
}

// ================================================================ gather kernels
// High-occupancy, bucket-CSR: block's buckets are one contiguous aligned range.

// fp8 gather (layers 1,2): 32 nodes/block, 8 lanes/node own uint4 chunks —
// half the VMEM instructions of the 16-lane/uint2 version at equal bytes.
// Accumulators are f32x4 SSA vectors (NOT float[16] array params — R6's
// spill cause); __launch_bounds__(256,4) gives 128-VGPR headroom, need ~64.
__global__ __launch_bounds__(256, 4) void gather_fp8_kernel(
    const uchar_t* __restrict__ Hn, const int* __restrict__ degv,
    const ushort_t* __restrict__ colb, ushort_t* __restrict__ Agg) {
  __shared__ ushort_t scol[32 * BCAP];  // 4 KB
  const int tid = threadIdx.x;
  const int n0 = blockIdx.x * 32;
  int nblk = N_NODES - n0;
  if (nblk > 32) nblk = 32;
  {
    const uint_t* cb = (const uint_t*)(colb + ((size_t)n0 << 6));
    uint_t* sc = (uint_t*)scol;
    for (int i = tid; i < nblk * 32; i += 256) sc[i] = cb[i];
  }
  __syncthreads();
  const int ln = tid >> 3;   // node slot 0..31
  const int node = n0 + ln;
  const int h = tid & 7;     // uint4 index within the 128B row
  if (node >= N_NODES) return;
  int nd = degv[node];
  float inv = 1.0f / fmaxf((float)nd, 1.0f);
  if (nd > BCAP) nd = BCAP;
  const ushort_t* cp = scol + (ln << 6);
  const uint4* Hu = (const uint4*)Hn;  // row stride 8 uint4 (128 B)
  f32x4 A = {0.f, 0.f, 0.f, 0.f}, B = A, C = A, D = A;
  for (int e = 0; e < nd; e += 8) {
    uint4 u[8];
#pragma unroll
    for (int q = 0; q < 8; q++) {
      int cc = (e + q < nd) ? (int)cp[e + q] : N_NODES;  // sentinel zero row
      u[q] = Hu[(size_t)cc * 8 + h];
    }
#pragma unroll
    for (int q = 0; q < 8; q++) cvt16(u[q], A, B, C, D);
  }
  uint4 o0, o1;
  o0.x = pack2(A[0] * inv, A[1] * inv);
  o0.y = pack2(A[2] * inv, A[3] * inv);
  o0.z = pack2(B[0] * inv, B[1] * inv);
  o0.w = pack2(B[2] * inv, B[3] * inv);
  o1.x = pack2(C[0] * inv, C[1] * inv);
  o1.y = pack2(C[2] * inv, C[3] * inv);
  o1.z = pack2(D[0] * inv, D[1] * inv);
  o1.w = pack2(D[2] * inv, D[3] * inv);
  uint4* Ag4 = (uint4*)Agg;
  Ag4[(size_t)node * 16 + h * 2] = o0;
  Ag4[(size_t)node * 16 + h * 2 + 1] = o1;
}

// layer-0 gather over xb: 10 lanes/node x uint2, 6 nodes/wave, 24/block.
// Masked 8-deep with xb sentinel zero row (no serial tails).
__global__ __launch_bounds__(256, 8) void gather0_kernel(
    const uint_t* __restrict__ xb, const int* __restrict__ degv,
    const ushort_t* __restrict__ colb, uint_t* __restrict__ Agg0) {
  __shared__ ushort_t scol[24 * BCAP];  // 3 KB
  const int tid = threadIdx.x;
  const int n0 = blockIdx.x * 24;
  int nblk = N_NODES - n0;
  if (nblk > 24) nblk = 24;
  {
    const uint_t* cb = (const uint_t*)(colb + ((size_t)n0 << 6));
    uint_t* sc = (uint_t*)scol;
    for (int i = tid; i < nblk * 32; i += 256) sc[i] = cb[i];
  }
  __syncthreads();
  const int w = tid >> 6, l = tid & 63;
  const int g = l / 10;        // 0..6 (g==6 -> idle lanes 60..63)
  const int j2 = l - g * 10;   // uint2 index 0..9 within the 80B row
  const int node = n0 + w * 6 + g;
  if (g >= 6 || node >= N_NODES) return;
  int nd = degv[node];
  float inv = 1.0f / fmaxf((float)nd, 1.0f);
  if (nd > BCAP) nd = BCAP;
  const ushort_t* cp = scol + ((node - n0) << 6);
  const uint2* xb2 = (const uint2*)xb;  // row stride 10 uint2 (80 B)
  float a0 = 0.f, a1 = 0.f, a2 = 0.f, a3 = 0.f;
  for (int e = 0; e < nd; e += 8) {
    uint2 u[8];
#pragma unroll
    for (int q = 0; q < 8; q++) {
      int cc = (e + q < nd) ? (int)cp[e + q] : N_NODES;
      u[q] = xb2[(size_t)cc * 10 + j2];
    }
#pragma unroll
    for (int q = 0; q < 8; q++) {
      a0 += bf_lo(u[q].x);
      a1 += bf_hi(u[q].x);
      a2 += bf_lo(u[q].y);
      a3 += bf_hi(u[q].y);
    }
  }
  uint2 o;
  o.x = pack2(a0 * inv, a1 * inv);
  o.y = pack2(a2 * inv, a3 * inv);
  ((uint2*)Agg0)[(size_t)node * 10 + j2] = o;
}

// ================================================================ layer-0 GEMM
__global__ __launch_bounds__(256, 6) void gemm0_kernel(
    const uint_t* __restrict__ xb, const uint_t* __restrict__ Agg0,
    const ushort_t* __restrict__ WT, ushort_t* __restrict__ P,
    float* __restrict__ stats) {
  __shared__ __align__(16) uint_t aggA[64 * 52];  // 64 rows x 96 bf16 + pad
  __shared__ __align__(16) ushort_t sB[128 * 40];
  const int tid = threadIdx.x;
  const int row0 = blockIdx.x * 64;
  const int w = tid >> 6;
  const int l = tid & 63;

  // ---- stage A tile: agg pairs 0..18, self 19..37, zero 38..47
  for (int i = tid; i < 64 * 48; i += 256) {
    int r = i / 48, j = i - r * 48;
    int node = row0 + r;
    uint_t v = 0;
    if (node < N_NODES) {
      if (j < 19) v = Agg0[(size_t)node * 20 + j];
      else if (j < 38) v = xb[(size_t)node * 20 + (j - 19)];
    }
    aggA[r * 52 + j] = v;
  }

  // ---- K loop (Kc = 96)
  const int m = l & 15;
  const int quad = l >> 4;
  f32x4 acc[8];
#pragma unroll
  for (int ct = 0; ct < 8; ct++) acc[ct] = (f32x4){0.f, 0.f, 0.f, 0.f};

  for (int kk = 0; kk < 96; kk += 32) {
    __syncthreads();
    {
      const uint4* wp = (const uint4*)(WT + (kk >> 5) * 4096);
      uint4 v0 = wp[tid];
      uint4 v1 = wp[tid + 256];
      *((uint4*)&sB[(tid >> 2) * 40 + (tid & 3) * 8]) = v0;
      int t2 = tid + 256;
      *((uint4*)&sB[(t2 >> 2) * 40 + (t2 & 3) * 8]) = v1;
    }
    __syncthreads();
    bf16x8 a = *(const bf16x8*)((const ushort_t*)aggA + (w * 16 + m) * 104 +
                                kk + quad * 8);
#pragma unroll
    for (int ct = 0; ct < 8; ct++) {
      bf16x8 b = *(const bf16x8*)&sB[(ct * 16 + m) * 40 + quad * 8];
      acc[ct] = __builtin_amdgcn_mfma_f32_16x16x32_bf16(a, b, acc[ct], 0, 0, 0);
    }
  }

#pragma unroll
  for (int ct = 0; ct < 8; ct++) {
#pragma unroll
    for (int v = 0; v < 4; v++) {
      int row = row0 + w * 16 + quad * 4 + v;
      if (row < N_NODES) P[(size_t)row * 128 + ct * 16 + m] = f2bf(acc[ct][v]);
    }
  }

  float* red = (float*)sB;
  __syncthreads();
#pragma unroll
  for (int ct = 0; ct < 8; ct++) {
    float s = 0.f, q = 0.f;
#pragma unroll
    for (int v = 0; v < 4; v++) {
      s += acc[ct][v];
      q += acc[ct][v] * acc[ct][v];
    }
    float t;
    t = __shfl_xor(s, 16); s += t;
    t = __shfl_xor(s, 32); s += t;
    t = __shfl_xor(q, 16); q += t;
    t = __shfl_xor(q, 32); q += t;
    if (l < 16) {
      red[w * 256 + ct * 16 + l] = s;
      red[w * 256 + 128 + ct * 16 + l] = q;
    }
  }
  __syncthreads();
  if (tid < 128) {
    float s = 0.f, q = 0.f;
#pragma unroll
    for (int wv = 0; wv < 4; wv++) {
      s += red[wv * 256 + tid];
      q += red[wv * 256 + 128 + tid];
    }
    atomicAdd(&stats[tid], s);
    atomicAdd(&stats[128 + tid], q);
  }
}

// ================================================================ mid-layer GEMM
// A = [Agg (bf16, staged from global) | bn_relu(Pin) (on the fly)]
__global__ __launch_bounds__(256, 4) void gemm_mid_kernel(
    const ushort_t* __restrict__ Pin, const ushort_t* __restrict__ Agg,
    const float* __restrict__ stats_prev,
    const float* __restrict__ gamma, const float* __restrict__ beta,
    const ushort_t* __restrict__ WT,
    ushort_t* __restrict__ Pout, float* __restrict__ stats_out) {
  __shared__ __align__(16) uint_t aggu[64 * 68];
  __shared__ __align__(16) ushort_t sA[64 * 40];
  __shared__ __align__(16) ushort_t sB[128 * 40];
  __shared__ float ssc[256];
  const int tid = threadIdx.x;
  const int row0 = blockIdx.x * 64;

  if (tid < 128) {
    const float invN = 1.0f / (float)N_NODES;
    float mean = stats_prev[tid] * invN;
    float var = stats_prev[128 + tid] * invN - mean * mean;
    float scale = gamma[tid] * rsqrtf(var + BN_EPS);
    ssc[tid] = scale;
    ssc[128 + tid] = beta[tid] - mean * scale;
  }
  // ---- stage Agg tile (64 rows x 64 uints) into aggu (stride 68)
  {
    const uint4* Ag4 = (const uint4*)Agg;
    for (int i = tid; i < 64 * 16; i += 256) {
      int r = i >> 4, c = i & 15;
      int row = row0 + r;
      uint4 v = make_uint4(0, 0, 0, 0);
      if (row < N_NODES) v = Ag4[(size_t)row * 16 + c];
      *((uint4*)&aggu[r * 68 + c * 4]) = v;
    }
  }

  const int w = tid >> 6;
  const int l = tid & 63;
  const int m = l & 15;
  const int quad = l >> 4;
  f32x4 acc[8];
#pragma unroll
  for (int ct = 0; ct < 8; ct++) acc[ct] = (f32x4){0.f, 0.f, 0.f, 0.f};

  for (int kk = 0; kk < 256; kk += 32) {
    __syncthreads();
    {
      const uint4* wp = (const uint4*)(WT + (kk >> 5) * 4096);
      uint4 v0 = wp[tid];
      uint4 v1 = wp[tid + 256];
      *((uint4*)&sB[(tid >> 2) * 40 + (tid & 3) * 8]) = v0;
      int t2 = tid + 256;
      *((uint4*)&sB[(t2 >> 2) * 40 + (t2 & 3) * 8]) = v1;
    }
    if (kk >= 128) {
      int r = tid >> 2, c = tid & 3;
      int row = row0 + r;
      uint4 v = make_uint4(0, 0, 0, 0);
      if (row < N_NODES) {
        int pcol = kk - 128 + c * 8;
        uint4 u = *(const uint4*)(Pin + (size_t)row * 128 + pcol);
        uint_t in[4] = {u.x, u.y, u.z, u.w};
        uint_t ov[4];
#pragma unroll
        for (int p = 0; p < 4; p++) {
          int cc = pcol + 2 * p;
          float f0 = fmaxf(bf_lo(in[p]) * ssc[cc] + ssc[128 + cc], 0.f);
          float f1 = fmaxf(bf_hi(in[p]) * ssc[cc + 1] + ssc[128 + cc + 1], 0.f);
          ov[p] = pack2(f0, f1);
        }
        v = make_uint4(ov[0], ov[1], ov[2], ov[3]);
      }
      *((uint4*)&sA[r * 40 + c * 8]) = v;
    }
    __syncthreads();
    bf16x8 a;
    if (kk < 128)
      a = *(const bf16x8*)((const ushort_t*)aggu + (w * 16 + m) * 136 + kk + quad * 8);
    else
      a = *(const bf16x8*)&sA[(w * 16 + m) * 40 + quad * 8];
#pragma unroll
    for (int ct = 0; ct < 8; ct++) {
      bf16x8 bb = *(const bf16x8*)&sB[(ct * 16 + m) * 40 + quad * 8];
      acc[ct] = __builtin_amdgcn_mfma_f32_16x16x32_bf16(a, bb, acc[ct], 0, 0, 0);
    }
  }

#pragma unroll
  for (int ct = 0; ct < 8; ct++) {
#pragma unroll
    for (int v = 0; v < 4; v++) {
      int row = row0 + w * 16 + quad * 4 + v;
      if (row < N_NODES)
        Pout[(size_t)row * 128 + ct * 16 + m] = f2bf(acc[ct][v]);
    }
  }

  float* red = (float*)sA;
  __syncthreads();
#pragma unroll
  for (int ct = 0; ct < 8; ct++) {
    float ss = 0.f, q = 0.f;
#pragma unroll
    for (int v = 0; v < 4; v++) {
      ss += acc[ct][v];
      q += acc[ct][v] * acc[ct][v];
    }
    float t;
    t = __shfl_xor(ss, 16); ss += t;
    t = __shfl_xor(ss, 32); ss += t;
    t = __shfl_xor(q, 16); q += t;
    t = __shfl_xor(q, 32); q += t;
    if (l < 16) {
      red[w * 256 + ct * 16 + l] = ss;
      red[w * 256 + 128 + ct * 16 + l] = q;
    }
  }
  __syncthreads();
  if (tid < 128) {
    float ss = 0.f, q = 0.f;
#pragma unroll
    for (int wv = 0; wv < 4; wv++) {
      ss += red[wv * 256 + tid];
      q += red[wv * 256 + 128 + tid];
    }
    atomicAdd(&stats_out[tid], ss);
    atomicAdd(&stats_out[128 + tid], q);
  }
}

// ================================================================ pool + readout
__global__ __launch_bounds__(128) void pool_readout_kernel(
    const ushort_t* __restrict__ P, const float* __restrict__ stats,
    const float* __restrict__ gamma, const float* __restrict__ beta,
    const int* __restrict__ batch, const float* __restrict__ rW1,
    const float* __restrict__ rb1, const float* __restrict__ rW2,
    const float* __restrict__ rb2, float* __restrict__ out) {
  int g = blockIdx.x;
  int t = threadIdx.x;
  int lo = 0, hi = N_NODES;
  while (lo < hi) { int mid = (lo + hi) >> 1; if (batch[mid] < g) lo = mid + 1; else hi = mid; }
  int gs = lo;
  hi = N_NODES;
  while (lo < hi) { int mid = (lo + hi) >> 1; if (batch[mid] < g + 1) lo = mid + 1; else hi = mid; }
  int ge = lo;
  const float invN = 1.0f / (float)N_NODES;
  float mean = stats[t] * invN;
  float var = stats[128 + t] * invN - mean * mean;
  float s = gamma[t] * rsqrtf(var + BN_EPS);
  float b = beta[t] - mean * s;
  float acc = 0.f;
  const ushort_t* pr = P + (size_t)gs * 128 + t;
  for (int r = gs; r < ge; r++, pr += 128)
    acc += fmaxf(__uint_as_float(((uint_t)*pr) << 16) * s + b, 0.f);
  __shared__ float pl[128];
  pl[t] = acc / fmaxf((float)(ge - gs), 1.f);
  __syncthreads();
  if (t < 64) {
    float h1 = rb1[t];
    for (int k = 0; k < 128; k++) h1 += pl[k] * rW1[k * 64 + t];
    h1 = fmaxf(h1, 0.f) * rW2[t];
#pragma unroll
    for (int off = 32; off > 0; off >>= 1) h1 += __shfl_down(h1, off);
    if (t == 0) out[g] = h1 + rb2[0];
  }
}

// ================================================================ launch
extern "C" void kernel_launch(void* const* d_in, const int* in_sizes, int n_in,
                              void* d_out, int out_size, void* d_ws, size_t ws_size,
                              hipStream_t stream) {
  const float* x     = (const float*)d_in[0];
  const int*   ei    = (const int*)d_in[1];
  const int*   src   = ei;
  const int*   dst   = ei + N_EDGES;
  const int*   batch = (const int*)d_in[2];
  const float* Wl0   = (const float*)d_in[3];
  const float* Wr0   = (const float*)d_in[4];
  const float* Wl    = (const float*)d_in[6];
  const float* Wr    = (const float*)d_in[7];
  const float* gamma = (const float*)d_in[9];
  const float* beta  = (const float*)d_in[10];
  const float* rW1   = (const float*)d_in[11];
  const float* rb1   = (const float*)d_in[12];
  const float* rW2   = (const float*)d_in[13];
  const float* rb2   = (const float*)d_in[14];
  float* out = (float*)d_out;

  char* ws = (char*)d_ws;
  size_t off = 0;
  auto alloc = [&](size_t bytes) -> void* {
    void* p = ws + off;
    off = (off + bytes + 255) & ~(size_t)255;
    return p;
  };
  uint_t*   xb    = (uint_t*)alloc((size_t)(N_NODES + 1) * 20 * 4);
  ushort_t* Pa    = (ushort_t*)alloc((size_t)N_NODES * 128 * 2);
  ushort_t* Pb    = (ushort_t*)alloc((size_t)N_NODES * 128 * 2);
  uchar_t*  Ha    = (uchar_t*)alloc((size_t)(N_NODES + 1) * 128);
  uchar_t*  Hb    = (uchar_t*)alloc((size_t)(N_NODES + 1) * 128);
  ushort_t* Agg   = (ushort_t*)alloc((size_t)N_NODES * 128 * 2);  // bf16 gather out
  uint_t*   Agg0  = (uint_t*)Agg;  // alias: layer-0 gather (4 MB), dead before gather1
  ushort_t* WT0   = (ushort_t*)alloc((size_t)128 * 96 * 2);
  ushort_t* WT1   = (ushort_t*)alloc((size_t)128 * 256 * 2);
  ushort_t* WT2   = (ushort_t*)alloc((size_t)128 * 256 * 2);
  int*      cursor= (int*)alloc((size_t)N_NODES * 4);             // doubles as degree
  ushort_t* colb  = (ushort_t*)alloc((size_t)N_NODES * BCAP * 2); // bucket CSR
  float*    stats = (float*)alloc(768 * 4);  // 3 layers x {sum[128],sumsq[128]}

  const int gemm_blocks = (N_NODES + 63) / 64;
  const int PREP_TOTAL = WP0 + 2 * WP1 + (N_NODES + 1) * 20;
  const int PREP_BLOCKS = (PREP_TOTAL + 255) / 256;
  const int FILL_BLOCKS = 2048;
  const int NORM_BLOCKS = (N_NODES * 16 + 255) / 256;
  const int GATHER_BLOCKS = (N_NODES + 31) / 32;   // 1563
  const int GATHER0_BLOCKS = (N_NODES + 23) / 24;  // 2084

  // ---- prep (weights/xb/stats/sentinels) + bucket fill in one launch
  hipMemsetAsync(cursor, 0, (size_t)N_NODES * 4, stream);
  prep_fill_kernel<<<PREP_BLOCKS + FILL_BLOCKS, 256, 0, stream>>>(
      Wl0, Wr0, Wl, Wr, x, src, dst, WT0, WT1, WT2, xb, stats, cursor, colb,
      Ha, Hb, PREP_BLOCKS);

  // ---- layer 0: gather (high-occupancy) then GEMM -> Pa (bf16)
  gather0_kernel<<<GATHER0_BLOCKS, 256, 0, stream>>>(xb, cursor, colb, Agg0);
  gemm0_kernel<<<gemm_blocks, 256, 0, stream>>>(xb, Agg0, WT0, Pa, stats);

  // ---- normalize layer-0 output -> Ha (fp8 of relu(bn(h0)))
  normalize_kernel<<<NORM_BLOCKS, 256, 0, stream>>>(Pa, stats, gamma, beta, Ha);

  // ---- layer 1: gather Ha -> Agg; GEMM (self Pa) -> Pb
  gather_fp8_kernel<<<GATHER_BLOCKS, 256, 0, stream>>>(Ha, cursor, colb, Agg);
  gemm_mid_kernel<<<gemm_blocks, 256, 0, stream>>>(
      Pa, Agg, stats, gamma, beta, WT1, Pb, stats + 256);

  // ---- normalize layer-1 output -> Hb
  normalize_kernel<<<NORM_BLOCKS, 256, 0, stream>>>(Pb, stats + 256,
                                                    gamma + 128, beta + 128, Hb);

  // ---- layer 2: gather Hb -> Agg; GEMM (self Pb) -> Pa
  gather_fp8_kernel<<<GATHER_BLOCKS, 256, 0, stream>>>(Hb, cursor, colb, Agg);
  gemm_mid_kernel<<<gemm_blocks, 256, 0, stream>>>(
      Pb, Agg, stats + 256, gamma + 128, beta + 128, WT2, Pa, stats + 512);

  // ---- fused global mean pool (final BN inline) + readout
  pool_readout_kernel<<<N_GRAPHS, 128, 0, stream>>>(
      Pa, stats + 512, gamma + 256, beta + 256, batch, rW1, rb1, rW2, rb2, out);
}

// Round 13
// 299.582 us; speedup vs baseline: 1.0965x; 1.0965x over previous
//
#include <hip/hip_runtime.h>

#define N_NODES 50000
#define N_EDGES 800000
#define N_GRAPHS 2000
#define BN_EPS 1e-5f
#define FSHARD 12500  // fill: N_NODES / 4
#define BCAP 64       // bucket capacity per node (P(deg>64) ~ 1e-22 @ Poisson(16))

typedef unsigned short ushort_t;
typedef unsigned int uint_t;
typedef unsigned char uchar_t;
using bf16x8 = __attribute__((ext_vector_type(8))) short;
using f32x4  = __attribute__((ext_vector_type(4))) float;
using vf2    = __attribute__((ext_vector_type(2))) float;

__device__ inline float bf_lo(uint_t u) { return __uint_as_float(u << 16); }
__device__ inline float bf_hi(uint_t u) { return __uint_as_float(u & 0xffff0000u); }
__device__ inline ushort_t f2bf(float f) {  // round-to-nearest-even
  uint_t u = __float_as_uint(f);
  return (ushort_t)((u + 0x7fffu + ((u >> 16) & 1u)) >> 16);
}
__device__ inline uint_t pack2(float a, float b) {
  return (uint_t)f2bf(a) | ((uint_t)f2bf(b) << 16);
}
// GATHER GEOMETRY AXIS CLOSED (R6 + R12): 16 lanes/node x uint2 @ 8 waves/EU
// is the measured optimum. uint4 x8 with float[16] array spilled (R6, 170MB
// scratch); uint4 x8 with f32x4 SSA + (256,4) halved occupancy and lost 14us
// per gather (R12). Do not revisit without new counter evidence.
__device__ inline void cvt_acc(uint2 u, float a[8]) {
  vf2 f01 = __builtin_amdgcn_cvt_pk_f32_fp8((int)u.x, false);
  vf2 f23 = __builtin_amdgcn_cvt_pk_f32_fp8((int)u.x, true);
  vf2 f45 = __builtin_amdgcn_cvt_pk_f32_fp8((int)u.y, false);
  vf2 f67 = __builtin_amdgcn_cvt_pk_f32_fp8((int)u.y, true);
  a[0] += f01[0]; a[1] += f01[1]; a[2] += f23[0]; a[3] += f23[1];
  a[4] += f45[0]; a[5] += f45[1]; a[6] += f67[0]; a[7] += f67[1];
}

// ================================================================ prep + bucket-fill (one launch)
// Bucket CSR: colb[d*64 + p] via ONE device-scope atomic pass; cursor doubles
// as degree. FLOOR EVIDENCE (~43-45us, atomic op-rate ~18G/s): R6 3-phase LDS
// histogram (+100us), R8 XCD-local scope (+36us), R11 cursor line-padding
// (no change) all falsified. Do not revisit without new counter evidence.
#define WP0 (128 * 96)
#define WP1 (128 * 256)
__global__ void prep_fill_kernel(const float* __restrict__ Wl0,
                                 const float* __restrict__ Wr0,
                                 const float* __restrict__ Wl,
                                 const float* __restrict__ Wr,
                                 const float* __restrict__ x,
                                 const int* __restrict__ src,
                                 const int* __restrict__ dst,
                                 ushort_t* __restrict__ WT0,
                                 ushort_t* __restrict__ WT1,
                                 ushort_t* __restrict__ WT2,
                                 uint_t* __restrict__ xb,
                                 float* __restrict__ stats,
                                 int* __restrict__ cursor,
                                 ushort_t* __restrict__ colb,
                                 uchar_t* __restrict__ Hza,
                                 uchar_t* __restrict__ Hzb,
                                 int prep_blocks) {
  if ((int)blockIdx.x >= prep_blocks) {
    // ---- sharded bucket fill (4 shards for cursor/colb L2 locality)
    const int b2 = blockIdx.x - prep_blocks;
    const int shard = b2 & 3;
    const int lo = shard * FSHARD, hi = lo + FSHARD;
    const int nb = (gridDim.x - prep_blocks) >> 2, blk = b2 >> 2;
    for (int e = blk * blockDim.x + threadIdx.x; e < N_EDGES;
         e += nb * blockDim.x) {
      int d = dst[e];
      if (d >= lo && d < hi) {
        int p = atomicAdd(&cursor[d], 1);
        if (p < BCAP) colb[((size_t)d << 6) + p] = (ushort_t)src[e];
      }
    }
    return;
  }
  int idx = blockIdx.x * blockDim.x + threadIdx.x;
  if (idx < 768) stats[idx] = 0.f;
  if (idx < 32) {  // sentinel zero rows (fp8) for masked gather tails
    ((uint_t*)(Hza + (size_t)N_NODES * 128))[idx] = 0;
    ((uint_t*)(Hzb + (size_t)N_NODES * 128))[idx] = 0;
  }
  if (idx < WP0) {
    int c = idx / 96, k = idx - c * 96;
    float v = 0.f;
    if (k < 38) v = Wl0[k * 128 + c];
    else if (k < 76) v = Wr0[(k - 38) * 128 + c];
    WT0[(k >> 5) * 4096 + c * 32 + (k & 31)] = f2bf(v);
  } else if (idx < WP0 + 2 * WP1) {
    int i2 = idx - WP0;
    int layer = i2 / WP1;
    int j = i2 - layer * WP1;
    int c = j / 256, k = j - c * 256;
    const float* L = Wl + layer * 16384;
    const float* R = Wr + layer * 16384;
    float v = (k < 128) ? L[k * 128 + c] : R[(k - 128) * 128 + c];
    ushort_t* W = layer ? WT2 : WT1;
    W[(k >> 5) * 4096 + c * 32 + (k & 31)] = f2bf(v);
  } else if (idx < WP0 + 2 * WP1 + (N_NODES + 1) * 20) {
    // xb rows 0..N_NODES (row N_NODES = sentinel zero row for masked gather0)
    int j = idx - (WP0 + 2 * WP1);
    int row = j / 20, c2 = (j - row * 20) * 2;
    float v0 = (row < N_NODES && c2 < 38) ? x[row * 38 + c2] : 0.f;
    float v1 = (row < N_NODES && c2 + 1 < 38) ? x[row * 38 + c2 + 1] : 0.f;
    xb[j] = pack2(v0, v1);
  }
}

// ================================================================ normalize
// Hn[row] = fp8(relu(bn(P[row]))) — per-node, so the gather never redoes BN.
__global__ __launch_bounds__(256) void normalize_kernel(
    const ushort_t* __restrict__ P, const float* __restrict__ stats,
    const float* __restrict__ gamma, const float* __restrict__ beta,
    uchar_t* __restrict__ Hn) {
  __shared__ float ssc[256];
  const int tid = threadIdx.x;
  if (tid < 128) {
    const float invN = 1.0f / (float)N_NODES;
    float mean = stats[tid] * invN;
    float var = stats[128 + tid] * invN - mean * mean;
    float s = gamma[tid] * rsqrtf(var + BN_EPS);
    ssc[tid] = s;
    ssc[128 + tid] = beta[tid] - mean * s;
  }
  __syncthreads();
  int idx = blockIdx.x * 256 + tid;  // segment id = row*16 + seg (8 cols each)
  if (idx >= N_NODES * 16) return;
  int c0 = (idx & 15) * 8;
  uint4 u = *(const uint4*)(P + (size_t)idx * 8);
  uint_t in[4] = {u.x, u.y, u.z, u.w};
  float f[8];
#pragma unroll
  for (int p = 0; p < 4; p++) {
    int c = c0 + 2 * p;
    f[2 * p]     = fmaxf(bf_lo(in[p]) * ssc[c] + ssc[128 + c], 0.f);
    f[2 * p + 1] = fmaxf(bf_hi(in[p]) * ssc[c + 1] + ssc[128 + c + 1], 0.f);
  }
  int lo = __builtin_amdgcn_cvt_pk_fp8_f32(f[0], f[1], 0, false);
  lo = __builtin_amdgcn_cvt_pk_fp8_f32(f[2], f[3], lo, true);
  int hi = __builtin_amdgcn_cvt_pk_fp8_f32(f[4], f[5], 0, false);
  hi = __builtin_amdgcn_cvt_pk_fp8_f32(f[6], f[7], hi, true);
  uint2 o;
  o.x = (uint_t)lo;
  o.y = (uint_t)hi;
  *((uint2*)(Hn + (size_t)idx * 8)) = o;
}

// ================================================================ gather kernels
// High-occupancy, bucket-CSR: block's buckets are one contiguous aligned range.

// fp8 gather (layers 1,2): 16 nodes/block, 16 lanes/node own uint2 chunks.
// Masked 8-deep (no serial tails); out-of-range slots read the Hn sentinel
// zero row (single L2-hot line). Measured-best geometry (R9/R11 ~300us).
__global__ __launch_bounds__(256, 8) void gather_fp8_kernel(
    const uchar_t* __restrict__ Hn, const int* __restrict__ degv,
    const ushort_t* __restrict__ colb, ushort_t* __restrict__ Agg) {
  __shared__ ushort_t scol[16 * BCAP];
  const int tid = threadIdx.x;
  const int n0 = blockIdx.x * 16;
  {
    const uint_t* cb = (const uint_t*)(colb + ((size_t)n0 << 6));
    uint_t* sc = (uint_t*)scol;
    sc[tid] = cb[tid];
    sc[tid + 256] = cb[tid + 256];
  }
  __syncthreads();
  const int node = n0 + (tid >> 4);  // grid exact: node < N_NODES
  const int h = tid & 15;
  int nd = degv[node];
  float inv = 1.0f / fmaxf((float)nd, 1.0f);
  if (nd > BCAP) nd = BCAP;
  const ushort_t* cp = scol + ((tid >> 4) << 6);
  const uint2* Hu = (const uint2*)Hn;
  float a[8];
#pragma unroll
  for (int j = 0; j < 8; j++) a[j] = 0.f;
  for (int e = 0; e < nd; e += 8) {
    uint2 u[8];
#pragma unroll
    for (int q = 0; q < 8; q++) {
      int cc = (e + q < nd) ? (int)cp[e + q] : N_NODES;
      u[q] = Hu[(size_t)cc * 16 + h];
    }
#pragma unroll
    for (int q = 0; q < 8; q++) cvt_acc(u[q], a);
  }
  uint4 o;
  o.x = pack2(a[0] * inv, a[1] * inv);
  o.y = pack2(a[2] * inv, a[3] * inv);
  o.z = pack2(a[4] * inv, a[5] * inv);
  o.w = pack2(a[6] * inv, a[7] * inv);
  ((uint4*)Agg)[(size_t)node * 16 + h] = o;
}

// layer-0 gather over xb: 10 lanes/node x uint2, 6 nodes/wave, 24/block.
// Masked 8-deep with xb sentinel zero row (no serial tails).
__global__ __launch_bounds__(256, 8) void gather0_kernel(
    const uint_t* __restrict__ xb, const int* __restrict__ degv,
    const ushort_t* __restrict__ colb, uint_t* __restrict__ Agg0) {
  __shared__ ushort_t scol[24 * BCAP];  // 3 KB
  const int tid = threadIdx.x;
  const int n0 = blockIdx.x * 24;
  int nblk = N_NODES - n0;
  if (nblk > 24) nblk = 24;
  {
    const uint_t* cb = (const uint_t*)(colb + ((size_t)n0 << 6));
    uint_t* sc = (uint_t*)scol;
    for (int i = tid; i < nblk * 32; i += 256) sc[i] = cb[i];
  }
  __syncthreads();
  const int w = tid >> 6, l = tid & 63;
  const int g = l / 10;        // 0..6 (g==6 -> idle lanes 60..63)
  const int j2 = l - g * 10;   // uint2 index 0..9 within the 80B row
  const int node = n0 + w * 6 + g;
  if (g >= 6 || node >= N_NODES) return;
  int nd = degv[node];
  float inv = 1.0f / fmaxf((float)nd, 1.0f);
  if (nd > BCAP) nd = BCAP;
  const ushort_t* cp = scol + ((node - n0) << 6);
  const uint2* xb2 = (const uint2*)xb;  // row stride 10 uint2 (80 B)
  float a0 = 0.f, a1 = 0.f, a2 = 0.f, a3 = 0.f;
  for (int e = 0; e < nd; e += 8) {
    uint2 u[8];
#pragma unroll
    for (int q = 0; q < 8; q++) {
      int cc = (e + q < nd) ? (int)cp[e + q] : N_NODES;
      u[q] = xb2[(size_t)cc * 10 + j2];
    }
#pragma unroll
    for (int q = 0; q < 8; q++) {
      a0 += bf_lo(u[q].x);
      a1 += bf_hi(u[q].x);
      a2 += bf_lo(u[q].y);
      a3 += bf_hi(u[q].y);
    }
  }
  uint2 o;
  o.x = pack2(a0 * inv, a1 * inv);
  o.y = pack2(a2 * inv, a3 * inv);
  ((uint2*)Agg0)[(size_t)node * 10 + j2] = o;
}

// ================================================================ layer-0 GEMM
__global__ __launch_bounds__(256, 6) void gemm0_kernel(
    const uint_t* __restrict__ xb, const uint_t* __restrict__ Agg0,
    const ushort_t* __restrict__ WT, ushort_t* __restrict__ P,
    float* __restrict__ stats) {
  __shared__ __align__(16) uint_t aggA[64 * 52];  // 64 rows x 96 bf16 + pad
  __shared__ __align__(16) ushort_t sB[128 * 40];
  const int tid = threadIdx.x;
  const int row0 = blockIdx.x * 64;
  const int w = tid >> 6;
  const int l = tid & 63;

  // ---- stage A tile: agg pairs 0..18, self 19..37, zero 38..47
  for (int i = tid; i < 64 * 48; i += 256) {
    int r = i / 48, j = i - r * 48;
    int node = row0 + r;
    uint_t v = 0;
    if (node < N_NODES) {
      if (j < 19) v = Agg0[(size_t)node * 20 + j];
      else if (j < 38) v = xb[(size_t)node * 20 + (j - 19)];
    }
    aggA[r * 52 + j] = v;
  }

  // ---- K loop (Kc = 96)
  const int m = l & 15;
  const int quad = l >> 4;
  f32x4 acc[8];
#pragma unroll
  for (int ct = 0; ct < 8; ct++) acc[ct] = (f32x4){0.f, 0.f, 0.f, 0.f};

  for (int kk = 0; kk < 96; kk += 32) {
    __syncthreads();
    {
      const uint4* wp = (const uint4*)(WT + (kk >> 5) * 4096);
      uint4 v0 = wp[tid];
      uint4 v1 = wp[tid + 256];
      *((uint4*)&sB[(tid >> 2) * 40 + (tid & 3) * 8]) = v0;
      int t2 = tid + 256;
      *((uint4*)&sB[(t2 >> 2) * 40 + (t2 & 3) * 8]) = v1;
    }
    __syncthreads();
    bf16x8 a = *(const bf16x8*)((const ushort_t*)aggA + (w * 16 + m) * 104 +
                                kk + quad * 8);
#pragma unroll
    for (int ct = 0; ct < 8; ct++) {
      bf16x8 b = *(const bf16x8*)&sB[(ct * 16 + m) * 40 + quad * 8];
      acc[ct] = __builtin_amdgcn_mfma_f32_16x16x32_bf16(a, b, acc[ct], 0, 0, 0);
    }
  }

#pragma unroll
  for (int ct = 0; ct < 8; ct++) {
#pragma unroll
    for (int v = 0; v < 4; v++) {
      int row = row0 + w * 16 + quad * 4 + v;
      if (row < N_NODES) P[(size_t)row * 128 + ct * 16 + m] = f2bf(acc[ct][v]);
    }
  }

  float* red = (float*)sB;
  __syncthreads();
#pragma unroll
  for (int ct = 0; ct < 8; ct++) {
    float s = 0.f, q = 0.f;
#pragma unroll
    for (int v = 0; v < 4; v++) {
      s += acc[ct][v];
      q += acc[ct][v] * acc[ct][v];
    }
    float t;
    t = __shfl_xor(s, 16); s += t;
    t = __shfl_xor(s, 32); s += t;
    t = __shfl_xor(q, 16); q += t;
    t = __shfl_xor(q, 32); q += t;
    if (l < 16) {
      red[w * 256 + ct * 16 + l] = s;
      red[w * 256 + 128 + ct * 16 + l] = q;
    }
  }
  __syncthreads();
  if (tid < 128) {
    float s = 0.f, q = 0.f;
#pragma unroll
    for (int wv = 0; wv < 4; wv++) {
      s += red[wv * 256 + tid];
      q += red[wv * 256 + 128 + tid];
    }
    atomicAdd(&stats[tid], s);
    atomicAdd(&stats[128 + tid], q);
  }
}

// ================================================================ mid-layer GEMM
// A = [Agg (bf16, staged from global) | bn_relu(Pin) (on the fly)]
__global__ __launch_bounds__(256, 4) void gemm_mid_kernel(
    const ushort_t* __restrict__ Pin, const ushort_t* __restrict__ Agg,
    const float* __restrict__ stats_prev,
    const float* __restrict__ gamma, const float* __restrict__ beta,
    const ushort_t* __restrict__ WT,
    ushort_t* __restrict__ Pout, float* __restrict__ stats_out) {
  __shared__ __align__(16) uint_t aggu[64 * 68];
  __shared__ __align__(16) ushort_t sA[64 * 40];
  __shared__ __align__(16) ushort_t sB[128 * 40];
  __shared__ float ssc[256];
  const int tid = threadIdx.x;
  const int row0 = blockIdx.x * 64;

  if (tid < 128) {
    const float invN = 1.0f / (float)N_NODES;
    float mean = stats_prev[tid] * invN;
    float var = stats_prev[128 + tid] * invN - mean * mean;
    float scale = gamma[tid] * rsqrtf(var + BN_EPS);
    ssc[tid] = scale;
    ssc[128 + tid] = beta[tid] - mean * scale;
  }
  // ---- stage Agg tile (64 rows x 64 uints) into aggu (stride 68)
  {
    const uint4* Ag4 = (const uint4*)Agg;
    for (int i = tid; i < 64 * 16; i += 256) {
      int r = i >> 4, c = i & 15;
      int row = row0 + r;
      uint4 v = make_uint4(0, 0, 0, 0);
      if (row < N_NODES) v = Ag4[(size_t)row * 16 + c];
      *((uint4*)&aggu[r * 68 + c * 4]) = v;
    }
  }

  const int w = tid >> 6;
  const int l = tid & 63;
  const int m = l & 15;
  const int quad = l >> 4;
  f32x4 acc[8];
#pragma unroll
  for (int ct = 0; ct < 8; ct++) acc[ct] = (f32x4){0.f, 0.f, 0.f, 0.f};

  for (int kk = 0; kk < 256; kk += 32) {
    __syncthreads();
    {
      const uint4* wp = (const uint4*)(WT + (kk >> 5) * 4096);
      uint4 v0 = wp[tid];
      uint4 v1 = wp[tid + 256];
      *((uint4*)&sB[(tid >> 2) * 40 + (tid & 3) * 8]) = v0;
      int t2 = tid + 256;
      *((uint4*)&sB[(t2 >> 2) * 40 + (t2 & 3) * 8]) = v1;
    }
    if (kk >= 128) {
      int r = tid >> 2, c = tid & 3;
      int row = row0 + r;
      uint4 v = make_uint4(0, 0, 0, 0);
      if (row < N_NODES) {
        int pcol = kk - 128 + c * 8;
        uint4 u = *(const uint4*)(Pin + (size_t)row * 128 + pcol);
        uint_t in[4] = {u.x, u.y, u.z, u.w};
        uint_t ov[4];
#pragma unroll
        for (int p = 0; p < 4; p++) {
          int cc = pcol + 2 * p;
          float f0 = fmaxf(bf_lo(in[p]) * ssc[cc] + ssc[128 + cc], 0.f);
          float f1 = fmaxf(bf_hi(in[p]) * ssc[cc + 1] + ssc[128 + cc + 1], 0.f);
          ov[p] = pack2(f0, f1);
        }
        v = make_uint4(ov[0], ov[1], ov[2], ov[3]);
      }
      *((uint4*)&sA[r * 40 + c * 8]) = v;
    }
    __syncthreads();
    bf16x8 a;
    if (kk < 128)
      a = *(const bf16x8*)((const ushort_t*)aggu + (w * 16 + m) * 136 + kk + quad * 8);
    else
      a = *(const bf16x8*)&sA[(w * 16 + m) * 40 + quad * 8];
#pragma unroll
    for (int ct = 0; ct < 8; ct++) {
      bf16x8 bb = *(const bf16x8*)&sB[(ct * 16 + m) * 40 + quad * 8];
      acc[ct] = __builtin_amdgcn_mfma_f32_16x16x32_bf16(a, bb, acc[ct], 0, 0, 0);
    }
  }

#pragma unroll
  for (int ct = 0; ct < 8; ct++) {
#pragma unroll
    for (int v = 0; v < 4; v++) {
      int row = row0 + w * 16 + quad * 4 + v;
      if (row < N_NODES)
        Pout[(size_t)row * 128 + ct * 16 + m] = f2bf(acc[ct][v]);
    }
  }

  float* red = (float*)sA;
  __syncthreads();
#pragma unroll
  for (int ct = 0; ct < 8; ct++) {
    float ss = 0.f, q = 0.f;
#pragma unroll
    for (int v = 0; v < 4; v++) {
      ss += acc[ct][v];
      q += acc[ct][v] * acc[ct][v];
    }
    float t;
    t = __shfl_xor(ss, 16); ss += t;
    t = __shfl_xor(ss, 32); ss += t;
    t = __shfl_xor(q, 16); q += t;
    t = __shfl_xor(q, 32); q += t;
    if (l < 16) {
      red[w * 256 + ct * 16 + l] = ss;
      red[w * 256 + 128 + ct * 16 + l] = q;
    }
  }
  __syncthreads();
  if (tid < 128) {
    float ss = 0.f, q = 0.f;
#pragma unroll
    for (int wv = 0; wv < 4; wv++) {
      ss += red[wv * 256 + tid];
      q += red[wv * 256 + 128 + tid];
    }
    atomicAdd(&stats_out[tid], ss);
    atomicAdd(&stats_out[128 + tid], q);
  }
}

// ================================================================ pool + readout
__global__ __launch_bounds__(128) void pool_readout_kernel(
    const ushort_t* __restrict__ P, const float* __restrict__ stats,
    const float* __restrict__ gamma, const float* __restrict__ beta,
    const int* __restrict__ batch, const float* __restrict__ rW1,
    const float* __restrict__ rb1, const float* __restrict__ rW2,
    const float* __restrict__ rb2, float* __restrict__ out) {
  int g = blockIdx.x;
  int t = threadIdx.x;
  int lo = 0, hi = N_NODES;
  while (lo < hi) { int mid = (lo + hi) >> 1; if (batch[mid] < g) lo = mid + 1; else hi = mid; }
  int gs = lo;
  hi = N_NODES;
  while (lo < hi) { int mid = (lo + hi) >> 1; if (batch[mid] < g + 1) lo = mid + 1; else hi = mid; }
  int ge = lo;
  const float invN = 1.0f / (float)N_NODES;
  float mean = stats[t] * invN;
  float var = stats[128 + t] * invN - mean * mean;
  float s = gamma[t] * rsqrtf(var + BN_EPS);
  float b = beta[t] - mean * s;
  float acc = 0.f;
  const ushort_t* pr = P + (size_t)gs * 128 + t;
  for (int r = gs; r < ge; r++, pr += 128)
    acc += fmaxf(__uint_as_float(((uint_t)*pr) << 16) * s + b, 0.f);
  __shared__ float pl[128];
  pl[t] = acc / fmaxf((float)(ge - gs), 1.f);
  __syncthreads();
  if (t < 64) {
    float h1 = rb1[t];
    for (int k = 0; k < 128; k++) h1 += pl[k] * rW1[k * 64 + t];
    h1 = fmaxf(h1, 0.f) * rW2[t];
#pragma unroll
    for (int off = 32; off > 0; off >>= 1) h1 += __shfl_down(h1, off);
    if (t == 0) out[g] = h1 + rb2[0];
  }
}

// ================================================================ launch
extern "C" void kernel_launch(void* const* d_in, const int* in_sizes, int n_in,
                              void* d_out, int out_size, void* d_ws, size_t ws_size,
                              hipStream_t stream) {
  const float* x     = (const float*)d_in[0];
  const int*   ei    = (const int*)d_in[1];
  const int*   src   = ei;
  const int*   dst   = ei + N_EDGES;
  const int*   batch = (const int*)d_in[2];
  const float* Wl0   = (const float*)d_in[3];
  const float* Wr0   = (const float*)d_in[4];
  const float* Wl    = (const float*)d_in[6];
  const float* Wr    = (const float*)d_in[7];
  const float* gamma = (const float*)d_in[9];
  const float* beta  = (const float*)d_in[10];
  const float* rW1   = (const float*)d_in[11];
  const float* rb1   = (const float*)d_in[12];
  const float* rW2   = (const float*)d_in[13];
  const float* rb2   = (const float*)d_in[14];
  float* out = (float*)d_out;

  char* ws = (char*)d_ws;
  size_t off = 0;
  auto alloc = [&](size_t bytes) -> void* {
    void* p = ws + off;
    off = (off + bytes + 255) & ~(size_t)255;
    return p;
  };
  uint_t*   xb    = (uint_t*)alloc((size_t)(N_NODES + 1) * 20 * 4);
  ushort_t* Pa    = (ushort_t*)alloc((size_t)N_NODES * 128 * 2);
  ushort_t* Pb    = (ushort_t*)alloc((size_t)N_NODES * 128 * 2);
  uchar_t*  Ha    = (uchar_t*)alloc((size_t)(N_NODES + 1) * 128);
  uchar_t*  Hb    = (uchar_t*)alloc((size_t)(N_NODES + 1) * 128);
  ushort_t* Agg   = (ushort_t*)alloc((size_t)N_NODES * 128 * 2);  // bf16 gather out
  uint_t*   Agg0  = (uint_t*)Agg;  // alias: layer-0 gather (4 MB), dead before gather1
  ushort_t* WT0   = (ushort_t*)alloc((size_t)128 * 96 * 2);
  ushort_t* WT1   = (ushort_t*)alloc((size_t)128 * 256 * 2);
  ushort_t* WT2   = (ushort_t*)alloc((size_t)128 * 256 * 2);
  int*      cursor= (int*)alloc((size_t)N_NODES * 4);             // doubles as degree
  ushort_t* colb  = (ushort_t*)alloc((size_t)N_NODES * BCAP * 2); // bucket CSR
  float*    stats = (float*)alloc(768 * 4);  // 3 layers x {sum[128],sumsq[128]}

  const int gemm_blocks = (N_NODES + 63) / 64;
  const int PREP_TOTAL = WP0 + 2 * WP1 + (N_NODES + 1) * 20;
  const int PREP_BLOCKS = (PREP_TOTAL + 255) / 256;
  const int FILL_BLOCKS = 2048;
  const int NORM_BLOCKS = (N_NODES * 16 + 255) / 256;
  const int GATHER_BLOCKS = N_NODES / 16;          // 3125 (exact)
  const int GATHER0_BLOCKS = (N_NODES + 23) / 24;  // 2084

  // ---- prep (weights/xb/stats/sentinels) + bucket fill in one launch
  hipMemsetAsync(cursor, 0, (size_t)N_NODES * 4, stream);
  prep_fill_kernel<<<PREP_BLOCKS + FILL_BLOCKS, 256, 0, stream>>>(
      Wl0, Wr0, Wl, Wr, x, src, dst, WT0, WT1, WT2, xb, stats, cursor, colb,
      Ha, Hb, PREP_BLOCKS);

  // ---- layer 0: gather (high-occupancy) then GEMM -> Pa (bf16)
  gather0_kernel<<<GATHER0_BLOCKS, 256, 0, stream>>>(xb, cursor, colb, Agg0);
  gemm0_kernel<<<gemm_blocks, 256, 0, stream>>>(xb, Agg0, WT0, Pa, stats);

  // ---- normalize layer-0 output -> Ha (fp8 of relu(bn(h0)))
  normalize_kernel<<<NORM_BLOCKS, 256, 0, stream>>>(Pa, stats, gamma, beta, Ha);

  // ---- layer 1: gather Ha -> Agg; GEMM (self Pa) -> Pb
  gather_fp8_kernel<<<GATHER_BLOCKS, 256, 0, stream>>>(Ha, cursor, colb, Agg);
  gemm_mid_kernel<<<gemm_blocks, 256, 0, stream>>>(
      Pa, Agg, stats, gamma, beta, WT1, Pb, stats + 256);

  // ---- normalize layer-1 output -> Hb
  normalize_kernel<<<NORM_BLOCKS, 256, 0, stream>>>(Pb, stats + 256,
                                                    gamma + 128, beta + 128, Hb);

  // ---- layer 2: gather Hb -> Agg; GEMM (self Pb) -> Pa
  gather_fp8_kernel<<<GATHER_BLOCKS, 256, 0, stream>>>(Hb, cursor, colb, Agg);
  gemm_mid_kernel<<<gemm_blocks, 256, 0, stream>>>(
      Pb, Agg, stats + 256, gamma + 128, beta + 128, WT2, Pa, stats + 512);

  // ---- fused global mean pool (final BN inline) + readout
  pool_readout_kernel<<<N_GRAPHS, 128, 0, stream>>>(
      Pa, stats + 512, gamma + 256, beta + 256, batch, rW1, rb1, rW2, rb2, out);
}